// Round 9
// baseline (640.712 us; speedup 1.0000x reference)
//
#include <hip/hip_runtime.h>

#define BN_EPS 1e-5f

typedef unsigned short us;

__device__ __forceinline__ float bf2f(us u) {
    union { unsigned int i; float f; } v; v.i = ((unsigned int)u) << 16; return v.f;
}
__device__ __forceinline__ us f2bf(float f) {
    unsigned int x = __float_as_uint(f);
    x += 0x7fffu + ((x >> 16) & 1u);
    return (us)(x >> 16);
}
__device__ __forceinline__ float ldf(const void* p, size_t i, int f32) {
    return f32 ? ((const float*)p)[i] : bf2f(((const us*)p)[i]);
}

__global__ void detect_kernel(const unsigned int* __restrict__ g, int* __restrict__ flag) {
    if (threadIdx.x == 0 && blockIdx.x == 0)
        *flag = ((g[0] & 0xFFFFu) == 0u) ? 1 : 0;
}

// ---------------------------------------------------------------------------
// Prep: coarse points -> f32 AoS (2x, 2y, 2z, s2). Exact _rn sequence;
// doubling exact (validated R14/R16/R17). Stages a-c.
// ---------------------------------------------------------------------------
__global__ __launch_bounds__(256)
void prep_aos_kernel(const void* __restrict__ p, float4* __restrict__ aos,
                     const int* __restrict__ pf32, int n)
{
    const int i = blockIdx.x * 256 + threadIdx.x;
    if (i >= n) return;
    const int f32 = *pf32;
    const float x = ldf(p, (size_t)3 * i + 0, f32);
    const float y = ldf(p, (size_t)3 * i + 1, f32);
    const float z = ldf(p, (size_t)3 * i + 2, f32);
    const float s2 = __fadd_rn(__fadd_rn(__fmul_rn(x, x), __fmul_rn(y, y)), __fmul_rn(z, z));
    aos[i] = make_float4(__fadd_rn(x, x), __fadd_rn(y, y), __fadd_rn(z, z), s2);
}

// ---------------------------------------------------------------------------
// Per-batch bitonic sort of coarse points by x (validated by R18's pass).
// ---------------------------------------------------------------------------
template<int NPB>
__global__ __launch_bounds__(NPB / 2)
void sort_aos_kernel(const void* __restrict__ p, const int* __restrict__ pf32,
                     float4* __restrict__ srt, int* __restrict__ jout)
{
    __shared__ float sk[NPB];
    __shared__ int   sj[NPB];
    const int f32 = *pf32;
    const int tid = threadIdx.x;
    const int base = blockIdx.x * NPB;
    for (int i = tid; i < NPB; i += NPB / 2) {
        sk[i] = ldf(p, (size_t)3 * (base + i) + 0, f32);
        sj[i] = i;
    }
    __syncthreads();
    for (int k = 2; k <= NPB; k <<= 1) {
        for (int j = k >> 1; j > 0; j >>= 1) {
            const int i = ((tid / j) * (j << 1)) + (tid % j);
            const int ixj = i + j;
            const bool up = ((i & k) == 0);
            const float a = sk[i], b = sk[ixj];
            const bool sw = up ? (a > b) : (a < b);
            if (sw) {
                sk[i] = b; sk[ixj] = a;
                const int t = sj[i]; sj[i] = sj[ixj]; sj[ixj] = t;
            }
            __syncthreads();
        }
    }
    for (int i = tid; i < NPB; i += NPB / 2) {
        const int jl = sj[i];
        const size_t b = (size_t)3 * (base + jl);
        const float x = ldf(p, b + 0, f32);
        const float y = ldf(p, b + 1, f32);
        const float z = ldf(p, b + 2, f32);
        const float s2 = __fadd_rn(__fadd_rn(__fmul_rn(x, x), __fmul_rn(y, y)),
                                   __fmul_rn(z, z));
        srt[base + i] = make_float4(__fadd_rn(x, x), __fadd_rn(y, y), __fadd_rn(z, z), s2);
        jout[base + i] = base + jl;
    }
}

// ---------------------------------------------------------------------------
// R19: bin-sort the FINE queries by x (grouping only — selection is
// order-invariant via lex inserts, so nondeterministic atomic order is safe).
// ---------------------------------------------------------------------------
__global__ __launch_bounds__(256)
void hist_kernel(const void* __restrict__ p, int* __restrict__ hist,
                 const int* __restrict__ pf32, int nf, int nfpb)
{
    const int i = blockIdx.x * 256 + threadIdx.x;
    if (i >= nf) return;
    const float x = ldf(p, (size_t)3 * i, *pf32);
    int bin = (int)(x * 128.0f);
    bin = bin < 0 ? 0 : (bin > 127 ? 127 : bin);
    atomicAdd(&hist[(i / nfpb) * 128 + bin], 1);
}

__global__ __launch_bounds__(64)
void prefix_kernel(const int* __restrict__ hist, int* __restrict__ cnt)
{
    const int b = threadIdx.x;
    if (b >= 8) return;
    int acc = 0;
    for (int i = 0; i < 128; ++i) {
        cnt[b * 128 + i] = acc;
        acc += hist[b * 128 + i];
    }
}

__global__ __launch_bounds__(256)
void scatter_kernel(const void* __restrict__ p, int* __restrict__ cnt,
                    int* __restrict__ qidx, const int* __restrict__ pf32,
                    int nf, int nfpb)
{
    const int i = blockIdx.x * 256 + threadIdx.x;
    if (i >= nf) return;
    const float x = ldf(p, (size_t)3 * i, *pf32);
    int bin = (int)(x * 128.0f);
    bin = bin < 0 ? 0 : (bin > 127 ? 127 : bin);
    const int b = i / nfpb;
    const int pos = atomicAdd(&cnt[b * 128 + bin], 1);
    qidx[b * nfpb + pos] = i;
}

// Branch-free lexicographic merge of two lex-sorted triples (validated R15-R18).
__device__ __forceinline__ void lexmerge33(
    const float a0, const int A0, const float a1, const int A1, const float a2, const int A2,
    const float b0, const int B0, const float b1, const int B1, const float b2, const int B2,
    float& m0, int& M0, float& m1, int& M1, float& m2, int& M2)
{
    const bool c1 = (a0 < b0) || (a0 == b0 && A0 < B0);
    m0 = c1 ? a0 : b0;  M0 = c1 ? A0 : B0;
    const float hAd = c1 ? a1 : a0;  const int hAi = c1 ? A1 : A0;
    const float hBd = c1 ? b0 : b1;  const int hBi = c1 ? B0 : B1;
    const bool c2 = (hAd < hBd) || (hAd == hBd && hAi < hBi);
    m1 = c2 ? hAd : hBd;  M1 = c2 ? hAi : hBi;
    const float gAd = c2 ? (c1 ? a2 : a1) : hAd;  const int gAi = c2 ? (c1 ? A2 : A1) : hAi;
    const float gBd = c2 ? hBd : (c1 ? b1 : b2);  const int gBi = c2 ? hBi : (c1 ? B1 : B2);
    const bool c3 = (gAd < gBd) || (gAd == gBd && gAi < gBi);
    m2 = c3 ? gAd : gBd;  M2 = c3 ? gAi : gBi;
}

// ---------------------------------------------------------------------------
// R19: windowed kNN, stage d, WAVE-UNIFORM walk over bin-sorted queries.
// Exactness (all pieces field-validated by R18's pass):
//  - lex (d2, global j) insert: order/partition-invariant selection.
//  - every processed candidate is real; extra processing is harmless; skips
//    happen only via the certified monotone bound (dq2 > 4*t2+4e-5, with
//    X > px2_l required on the right walk before the bound applies).
//  - walk covers [S,NPB) + [0,S-1] with S = first X >= wave-min(px2):
//    left positions have X < px2_l for ALL lanes (monotone certified);
//    right positions with X <= px2_l keep the lane alive (processed).
//  - queries bin-sorted by x => waves spatially coherent => sA[p] reads are
//    wave-uniform broadcasts (no LDS conflicts, shared termination).
// ---------------------------------------------------------------------------
template<int NPB, int C2, int QPB>
__global__ __launch_bounds__(512)
void knn_win2_kernel(const void* __restrict__ p_fine,
                     const float4* __restrict__ srt,
                     const int* __restrict__ jsrt,
                     const int* __restrict__ qidx,
                     const float* __restrict__ f_coarse,
                     const float* __restrict__ stats,
                     const void* __restrict__ gamma,
                     const void* __restrict__ beta,
                     float inv_n2,
                     float* __restrict__ up_out,
                     const int* __restrict__ pf32,
                     int nfpb)
{
    __shared__ __align__(16) float4 sA[NPB];
    __shared__ int   sJ[NPB];
    __shared__ float mrg_d[2 * QPB * 3];
    __shared__ int   mrg_i[2 * QPB * 3];
    __shared__ int   s_idx[QPB][3];
    __shared__ float s_w[QPB][3];
    __shared__ int   s_qrow[QPB];
    __shared__ float aff_a[C2], aff_b[C2];

    const int f32 = *pf32;
    const int tid = threadIdx.x;
    const int lane = tid & 63;
    const int wv = tid >> 6;          // 0..7
    const int g = wv >> 1;            // query group 0..3
    const int sp = wv & 1;            // split-wave 0/1
    const int cb = blockIdx.y * NPB;

    for (int i = tid; i < NPB; i += 512) { sA[i] = srt[cb + i]; sJ[i] = jsrt[cb + i]; }
    if (tid < QPB) s_qrow[tid] = qidx[blockIdx.y * nfpb + blockIdx.x * QPB + tid];
    for (int c = tid; c < C2; c += 512) {
        const float mu  = stats[c] * inv_n2;
        const float var = stats[C2 + c] * inv_n2 - mu * mu;
        const float a = ldf(gamma, c, f32) * rsqrtf(var + BN_EPS);
        aff_a[c] = a;
        aff_b[c] = ldf(beta, c, f32) - mu * a;
    }
    __syncthreads();

    const int qrow = s_qrow[g * 64 + lane];
    const size_t pb = (size_t)qrow * 3;
    const float px = ldf(p_fine, pb + 0, f32);
    const float py = ldf(p_fine, pb + 1, f32);
    const float pz = ldf(p_fine, pb + 2, f32);
    const float s1 = __fadd_rn(__fadd_rn(__fmul_rn(px, px), __fmul_rn(py, py)),
                               __fmul_rn(pz, pz));
    const float px2 = __fadd_rn(px, px);

    // wave-min px2 (exact shfl reduce), then uniform binary search for S
    float pmn = px2;
    #pragma unroll
    for (int m = 1; m < 64; m <<= 1) pmn = fminf(pmn, __shfl_xor(pmn, m, 64));
    int lo = 0, hi = NPB;
    while (lo < hi) {
        const int mid = (lo + hi) >> 1;
        if (sA[mid].x < pmn) lo = mid + 1; else hi = mid;
    }
    const int S = lo;

    float t0 = 1e30f, t1 = 1e30f, t2 = 1e30f;
    int i0 = 0, i1 = 0, i2 = 0;

#define LEXINS(D, JJ) {                                                       \
    const bool l0 = (D) < t0 || ((D) == t0 && (JJ) < i0);                     \
    const bool l1 = (D) < t1 || ((D) == t1 && (JJ) < i1);                     \
    const bool l2 = (D) < t2 || ((D) == t2 && (JJ) < i2);                     \
    i2 = l1 ? i1 : (l2 ? (JJ) : i2);                                          \
    i1 = l0 ? i0 : (l1 ? (JJ) : i1);                                          \
    i0 = l0 ? (JJ) : i0;                                                      \
    const float q2 = l1 ? t1 : (l2 ? (D) : t2);                               \
    const float q1 = l0 ? t0 : (l1 ? (D) : t1);                               \
    t0 = l0 ? (D) : t0;  t1 = q1;  t2 = q2; }

    // right walk: p = S+sp, S+sp+2, ... (wave-uniform broadcast reads)
    {
        bool alive = true;
        for (int p = S + sp; p < NPB; p += 2) {
            if (!__any(alive)) break;
            const float4 C = sA[p];
            const float dq = __fsub_rn(px2, C.x);
            const float dq2 = __fmul_rn(dq, dq);
            const float dot2 = fmaf(pz, C.z, fmaf(py, C.y, __fmul_rn(px, C.x)));
            const float d = __fsub_rn(__fadd_rn(s1, C.w), dot2);
            LEXINS(d, sJ[p]);
            alive = alive && !((C.x > px2) && (dq2 > fmaf(4.0f, t2, 4e-5f)));
        }
    }
    // left walk: p = S-1-sp, ... (X < wave-min px2 <= px2_l: monotone bound)
    {
        bool alive = true;
        for (int p = S - 1 - sp; p >= 0; p -= 2) {
            if (!__any(alive)) break;
            const float4 C = sA[p];
            const float dq = __fsub_rn(px2, C.x);
            const float dq2 = __fmul_rn(dq, dq);
            const float dot2 = fmaf(pz, C.z, fmaf(py, C.y, __fmul_rn(px, C.x)));
            const float d = __fsub_rn(__fadd_rn(s1, C.w), dot2);
            LEXINS(d, sJ[p]);
            alive = alive && !(dq2 > fmaf(4.0f, t2, 4e-5f));
        }
    }
#undef LEXINS

    const int mb = (sp * QPB + g * 64 + lane) * 3;
    mrg_d[mb + 0] = t0;  mrg_i[mb + 0] = i0;
    mrg_d[mb + 1] = t1;  mrg_i[mb + 1] = i1;
    mrg_d[mb + 2] = t2;  mrg_i[mb + 2] = i2;
    __syncthreads();

    if (tid < QPB) {
        const int a = tid * 3, b = (QPB + tid) * 3;
        float d0, d1, d2; int j0, j1, j2;
        lexmerge33(mrg_d[a + 0], mrg_i[a + 0], mrg_d[a + 1], mrg_i[a + 1],
                   mrg_d[a + 2], mrg_i[a + 2],
                   mrg_d[b + 0], mrg_i[b + 0], mrg_d[b + 1], mrg_i[b + 1],
                   mrg_d[b + 2], mrg_i[b + 2],
                   d0, j0, d1, j1, d2, j2);
        s_idx[tid][0] = j0;  s_w[tid][0] = __fdiv_rn(1.0f, fmaxf(d0, 1e-16f));
        s_idx[tid][1] = j1;  s_w[tid][1] = __fdiv_rn(1.0f, fmaxf(d1, 1e-16f));
        s_idx[tid][2] = j2;  s_w[tid][2] = __fdiv_rn(1.0f, fmaxf(d2, 1e-16f));
    }
    __syncthreads();

    // gather: up = weighted sum of relu(BN(f_coarse)) rows, coalesced over c
    for (int p = wv; p < QPB; p += 8) {
        const int row = s_qrow[p];
        const int g0 = s_idx[p][0], g1 = s_idx[p][1], g2 = s_idx[p][2];
        const float w0 = s_w[p][0], w1 = s_w[p][1], w2 = s_w[p][2];
        const float den = __fadd_rn(__fadd_rn(w0, w1), w2);
        float* __restrict__ urow = up_out + (size_t)row * C2;
        for (int c = lane; c < C2; c += 64) {
            const float aa = aff_a[c], bb = aff_b[c];
            const float v0 = fmaxf(aa * f_coarse[(size_t)g0 * C2 + c] + bb, 0.f);
            const float v1 = fmaxf(aa * f_coarse[(size_t)g1 * C2 + c] + bb, 0.f);
            const float v2 = fmaxf(aa * f_coarse[(size_t)g2 * C2 + c] + bb, 0.f);
            const float num = fmaf(w2, v2, fmaf(w1, v1, __fmul_rn(w0, v0)));
            urow[c] = __fdiv_rn(num, den);
        }
    }
}

// ---------------------------------------------------------------------------
// kNN(k=3) + inverse-d2 interpolation (R17 verified path; stages a-c).
// ---------------------------------------------------------------------------
template<int MODE, int SPLIT, int LEN>
__global__ __launch_bounds__(64 * SPLIT, 8)
void knn_up_kernel(
    const void* __restrict__ p_fine,
    const float4* __restrict__ aos,
    const void* __restrict__ f_coarse,
    const float* __restrict__ stats,
    const void* __restrict__ gamma,
    const void* __restrict__ beta,
    float inv_n2,
    float* __restrict__ up_out,
    const int* __restrict__ pf32,
    int n2pb, int c2)
{
    __shared__ float mrg_d[SPLIT * 64 * 3];
    __shared__ int   mrg_i[SPLIT * 64 * 3];
    __shared__ float aff_a[256], aff_b[256];
    __shared__ int   s_idx[64][3];
    __shared__ float s_w[64][3];

    const int f32 = *pf32;
    const int tid = threadIdx.x;
    const int lane = tid & 63;
    const int wv = tid >> 6;
    const int cbase = blockIdx.y * n2pb;
    const int row0 = (blockIdx.y * gridDim.x + blockIdx.x) * 64;

    if (MODE == 1) {
        for (int c = tid; c < c2; c += 64 * SPLIT) {
            float mu  = stats[c] * inv_n2;
            float var = stats[c2 + c] * inv_n2 - mu * mu;
            float a = ldf(gamma, c, f32) * rsqrtf(var + BN_EPS);
            aff_a[c] = a;
            aff_b[c] = ldf(beta, c, f32) - mu * a;
        }
    }

    {
        const int row = row0 + lane;
        const size_t b = (size_t)row * 3;
        const float px = ldf(p_fine, b + 0, f32);
        const float py = ldf(p_fine, b + 1, f32);
        const float pz = ldf(p_fine, b + 2, f32);
        const float s1 = __fadd_rn(__fadd_rn(__fmul_rn(px, px), __fmul_rn(py, py)),
                                   __fmul_rn(pz, pz));
        const int jb = wv * LEN;
        unsigned long long spv = (unsigned long long)(const void*)(aos + cbase + jb);
        spv = ((unsigned long long)__builtin_amdgcn_readfirstlane((unsigned int)(spv >> 32)) << 32)
            |  (unsigned long long)__builtin_amdgcn_readfirstlane((unsigned int)spv);
        const float4* __restrict__ sl = (const float4*)spv;

        float t0 = 1e30f, t1 = 1e30f, t2 = 1e30f;
        int i0 = jb, i1 = jb, i2 = jb;

#define KNN_UPD(CQ, JJ) {                                                     \
        const float dot2 = fmaf(pz, (CQ).z, fmaf(py, (CQ).y,                  \
                                __fmul_rn(px, (CQ).x)));                      \
        const float d = __fsub_rn(__fadd_rn(s1, (CQ).w), dot2);               \
        const int jj = (JJ);                                                  \
        const bool a0 = d < t0, a1 = d < t1, a2 = d < t2;                     \
        i2 = a1 ? i1 : (a2 ? jj : i2);                                        \
        i1 = a0 ? i0 : (a1 ? jj : i1);                                        \
        i0 = a0 ? jj : i0;                                                    \
        const float nt1 = __builtin_amdgcn_fmed3f(d, t0, t1);                 \
        const float nt2 = __builtin_amdgcn_fmed3f(d, t1, t2);                 \
        t0 = fminf(d, t0);                                                    \
        t1 = nt1; t2 = nt2; }

        float4 ca = sl[0], cb = sl[1], cc = sl[2], cd = sl[3];
        for (int t = 0; t < LEN; t += 4) {
            float4 na, nb, nc, nd;
            const bool more = (t + 4) < LEN;
            if (more) { na = sl[t + 4]; nb = sl[t + 5]; nc = sl[t + 6]; nd = sl[t + 7]; }
            KNN_UPD(ca, jb + t + 0);
            KNN_UPD(cb, jb + t + 1);
            KNN_UPD(cc, jb + t + 2);
            KNN_UPD(cd, jb + t + 3);
            if (more) { ca = na; cb = nb; cc = nc; cd = nd; }
        }
#undef KNN_UPD

        const int mb = (wv * 64 + lane) * 3;
        mrg_d[mb + 0] = t0;  mrg_i[mb + 0] = cbase + i0;
        mrg_d[mb + 1] = t1;  mrg_i[mb + 1] = cbase + i1;
        mrg_d[mb + 2] = t2;  mrg_i[mb + 2] = cbase + i2;
    }
    __syncthreads();

    if (tid < 64) {
        float d0 = mrg_d[tid * 3 + 0], d1 = mrg_d[tid * 3 + 1], d2 = mrg_d[tid * 3 + 2];
        int   j0 = mrg_i[tid * 3 + 0], j1 = mrg_i[tid * 3 + 1], j2 = mrg_i[tid * 3 + 2];
        #pragma unroll
        for (int w = 1; w < SPLIT; ++w) {
            const int mb = (w * 64 + tid) * 3;
            const float e0 = mrg_d[mb + 0], e1 = mrg_d[mb + 1], e2 = mrg_d[mb + 2];
            const int   k0 = mrg_i[mb + 0], k1 = mrg_i[mb + 1], k2 = mrg_i[mb + 2];
            float n0, n1, n2v; int ni0, ni1, ni2;
            lexmerge33(d0, j0, d1, j1, d2, j2,
                       e0, k0, e1, k1, e2, k2,
                       n0, ni0, n1, ni1, n2v, ni2);
            d0 = n0; j0 = ni0; d1 = n1; j1 = ni1; d2 = n2v; j2 = ni2;
        }
        s_idx[tid][0] = j0;  s_w[tid][0] = __fdiv_rn(1.0f, fmaxf(d0, 1e-16f));
        s_idx[tid][1] = j1;  s_w[tid][1] = __fdiv_rn(1.0f, fmaxf(d1, 1e-16f));
        s_idx[tid][2] = j2;  s_w[tid][2] = __fdiv_rn(1.0f, fmaxf(d2, 1e-16f));
    }
    __syncthreads();

    for (int p = wv; p < 64; p += SPLIT) {
        const int row = row0 + p;
        const int g0 = s_idx[p][0], g1 = s_idx[p][1], g2 = s_idx[p][2];
        const float w0 = s_w[p][0], w1 = s_w[p][1], w2 = s_w[p][2];
        const float den = __fadd_rn(__fadd_rn(w0, w1), w2);
        float* __restrict__ urow = up_out + (size_t)row * c2;
        for (int c = lane; c < c2; c += 64) {
            float v0, v1, v2;
            if (MODE == 0) {
                v0 = ldf(f_coarse, (size_t)g0 * c2 + c, f32);
                v1 = ldf(f_coarse, (size_t)g1 * c2 + c, f32);
                v2 = ldf(f_coarse, (size_t)g2 * c2 + c, f32);
            } else {
                const float* fc = (const float*)f_coarse;
                const float aa = aff_a[c], bb = aff_b[c];
                v0 = fmaxf(aa * fc[(size_t)g0 * c2 + c] + bb, 0.f);
                v1 = fmaxf(aa * fc[(size_t)g1 * c2 + c] + bb, 0.f);
                v2 = fmaxf(aa * fc[(size_t)g2 * c2 + c] + bb, 0.f);
            }
            const float num = fmaf(w2, v2, fmaf(w1, v1, __fmul_rn(w0, v0)));
            urow[c] = __fdiv_rn(num, den);
        }
    }
}

// ---------------------------------------------------------------------------
// GEMM1: H = [f_fine | up] @ W + bias; register-prefetch double buffering;
// fused atomic column sum/sumsq. 64x64 tile, TK=16, 4x4/thread. c1 % 16 == 0.
// ---------------------------------------------------------------------------
__global__ __launch_bounds__(256)
void gemm1_bn_kernel(const void* __restrict__ Ffine,
                     const float* __restrict__ Up,
                     const void* __restrict__ W,
                     const void* __restrict__ bias,
                     float* __restrict__ H,
                     float* __restrict__ stats_out,
                     const int* __restrict__ pf32,
                     int M, int c1, int c2, int N)
{
    __shared__ __align__(16) float As[16][68];
    __shared__ __align__(16) float Bs[16][68];
    __shared__ float s_sum[64], s_sq[64];

    const int f32 = *pf32;
    const int K = c1 + c2;
    const int tid = threadIdx.x;
    const int tx = tid & 15, ty = tid >> 4;
    const int n0 = blockIdx.x * 64, m0 = blockIdx.y * 64;

    if (tid < 64) { s_sum[tid] = 0.f; s_sq[tid] = 0.f; }

    const int a_m = tid >> 2;
    const int a_k = (tid & 3) << 2;
    const int b_k = tid >> 4;
    const int b_n = (tid & 15) << 2;
    const int row = m0 + a_m;

    float avp[4]; float4 bvp;
    {
        const int k = a_k;
        if (k < c1) {
            if (f32) {
                const float4 v = *(const float4*)((const float*)Ffine + (size_t)row * c1 + k);
                avp[0] = v.x; avp[1] = v.y; avp[2] = v.z; avp[3] = v.w;
            } else {
                const ushort4 u = *(const ushort4*)((const us*)Ffine + (size_t)row * c1 + k);
                avp[0] = bf2f(u.x); avp[1] = bf2f(u.y); avp[2] = bf2f(u.z); avp[3] = bf2f(u.w);
            }
        } else {
            const float4 v = *(const float4*)(Up + (size_t)row * c2 + (k - c1));
            avp[0] = v.x; avp[1] = v.y; avp[2] = v.z; avp[3] = v.w;
        }
        bvp = make_float4(0.f, 0.f, 0.f, 0.f);
        if (n0 + b_n < N) {
            const size_t wi = (size_t)b_k * N + (n0 + b_n);
            if (f32) bvp = *(const float4*)((const float*)W + wi);
            else {
                const ushort4 u = *(const ushort4*)((const us*)W + wi);
                bvp = make_float4(bf2f(u.x), bf2f(u.y), bf2f(u.z), bf2f(u.w));
            }
        }
    }

    float acc[4][4] = {};

    for (int k0 = 0; k0 < K; k0 += 16) {
        #pragma unroll
        for (int i = 0; i < 4; ++i) As[a_k + i][a_m] = avp[i];
        *(float4*)&Bs[b_k][b_n] = bvp;
        __syncthreads();

        float avn[4]; float4 bvn;
        const int kn = k0 + 16;
        if (kn < K) {
            const int k = kn + a_k;
            if (k < c1) {
                if (f32) {
                    const float4 v = *(const float4*)((const float*)Ffine + (size_t)row * c1 + k);
                    avn[0] = v.x; avn[1] = v.y; avn[2] = v.z; avn[3] = v.w;
                } else {
                    const ushort4 u = *(const ushort4*)((const us*)Ffine + (size_t)row * c1 + k);
                    avn[0] = bf2f(u.x); avn[1] = bf2f(u.y); avn[2] = bf2f(u.z); avn[3] = bf2f(u.w);
                }
            } else {
                const float4 v = *(const float4*)(Up + (size_t)row * c2 + (k - c1));
                avn[0] = v.x; avn[1] = v.y; avn[2] = v.z; avn[3] = v.w;
            }
            bvn = make_float4(0.f, 0.f, 0.f, 0.f);
            if (n0 + b_n < N) {
                const size_t wi = (size_t)(kn + b_k) * N + (n0 + b_n);
                if (f32) bvn = *(const float4*)((const float*)W + wi);
                else {
                    const ushort4 u = *(const ushort4*)((const us*)W + wi);
                    bvn = make_float4(bf2f(u.x), bf2f(u.y), bf2f(u.z), bf2f(u.w));
                }
            }
        }

        #pragma unroll
        for (int kk = 0; kk < 16; ++kk) {
            const float4 a4 = *(const float4*)&As[kk][ty << 2];
            const float4 b4 = *(const float4*)&Bs[kk][tx << 2];
            const float aarr[4] = {a4.x, a4.y, a4.z, a4.w};
            const float barr[4] = {b4.x, b4.y, b4.z, b4.w};
            #pragma unroll
            for (int i = 0; i < 4; ++i)
                #pragma unroll
                for (int j = 0; j < 4; ++j)
                    acc[i][j] = fmaf(aarr[i], barr[j], acc[i][j]);
        }
        __syncthreads();

        if (kn < K) {
            #pragma unroll
            for (int i = 0; i < 4; ++i) avp[i] = avn[i];
            bvp = bvn;
        }
    }

    float bvals[4];
    const bool colsok = (n0 + (tx << 2)) < N;
    #pragma unroll
    for (int j = 0; j < 4; ++j) {
        const int n = n0 + (tx << 2) + j;
        bvals[j] = (n < N) ? ldf(bias, n, f32) : 0.f;
    }
    float ps[4] = {0.f, 0.f, 0.f, 0.f}, pq[4] = {0.f, 0.f, 0.f, 0.f};
    #pragma unroll
    for (int i = 0; i < 4; ++i) {
        float4 hv;
        float* hvp = (float*)&hv;
        #pragma unroll
        for (int j = 0; j < 4; ++j) {
            const float v = acc[i][j] + bvals[j];
            hvp[j] = v;
            ps[j] += v;
            pq[j] = fmaf(v, v, pq[j]);
        }
        if (colsok)
            *(float4*)(H + (size_t)(m0 + (ty << 2) + i) * N + n0 + (tx << 2)) = hv;
    }
    #pragma unroll
    for (int j = 0; j < 4; ++j) {
        atomicAdd(&s_sum[(tx << 2) + j], ps[j]);
        atomicAdd(&s_sq[(tx << 2) + j], pq[j]);
    }
    __syncthreads();
    if (tid < 64) {
        const int n = n0 + tid;
        if (n < N) {
            atomicAdd(&stats_out[n], s_sum[tid]);
            atomicAdd(&stats_out[N + n], s_sq[tid]);
        }
    }
}

// ---------------------------------------------------------------------------
// GEMM2: H = relu(BN(A)) @ W + bias; register-prefetch double buffering;
// affine on load; fused atomic stats out.
// ---------------------------------------------------------------------------
__global__ __launch_bounds__(256)
void gemm2_bn_kernel(const float* __restrict__ A,
                     const void* __restrict__ W,
                     const void* __restrict__ bias,
                     const float* __restrict__ stats_in,
                     const void* __restrict__ g_in,
                     const void* __restrict__ bt_in,
                     float inv_m,
                     float* __restrict__ H,
                     float* __restrict__ stats_out,
                     const int* __restrict__ pf32,
                     int M, int K, int N)
{
    __shared__ __align__(16) float As[16][68];
    __shared__ __align__(16) float Bs[16][68];
    __shared__ float aff_a[256], aff_b[256];
    __shared__ float s_sum[64], s_sq[64];

    const int f32 = *pf32;
    const int tid = threadIdx.x;
    const int tx = tid & 15, ty = tid >> 4;
    const int n0 = blockIdx.x * 64, m0 = blockIdx.y * 64;

    for (int c = tid; c < K; c += 256) {
        float mu  = stats_in[c] * inv_m;
        float var = stats_in[K + c] * inv_m - mu * mu;
        float a = ldf(g_in, c, f32) * rsqrtf(var + BN_EPS);
        aff_a[c] = a; aff_b[c] = ldf(bt_in, c, f32) - mu * a;
    }
    if (tid < 64) { s_sum[tid] = 0.f; s_sq[tid] = 0.f; }
    __syncthreads();

    const int a_m = tid >> 2;
    const int a_k = (tid & 3) << 2;
    const int b_k = tid >> 4;
    const int b_n = (tid & 15) << 2;
    const int row = m0 + a_m;

    float avp[4]; float4 bvp;
    {
        const float4 af = *(const float4*)(A + (size_t)row * K + a_k);
        avp[0] = af.x; avp[1] = af.y; avp[2] = af.z; avp[3] = af.w;
        bvp = make_float4(0.f, 0.f, 0.f, 0.f);
        if (n0 + b_n < N) {
            const size_t wi = (size_t)b_k * N + (n0 + b_n);
            if (f32) bvp = *(const float4*)((const float*)W + wi);
            else {
                const ushort4 u = *(const ushort4*)((const us*)W + wi);
                bvp = make_float4(bf2f(u.x), bf2f(u.y), bf2f(u.z), bf2f(u.w));
            }
        }
    }

    float acc[4][4] = {};

    for (int k0 = 0; k0 < K; k0 += 16) {
        #pragma unroll
        for (int i = 0; i < 4; ++i)
            As[a_k + i][a_m] = fmaxf(fmaf(aff_a[k0 + a_k + i], avp[i], aff_b[k0 + a_k + i]), 0.f);
        *(float4*)&Bs[b_k][b_n] = bvp;
        __syncthreads();

        float avn[4]; float4 bvn;
        const int kn = k0 + 16;
        if (kn < K) {
            const float4 af = *(const float4*)(A + (size_t)row * K + (kn + a_k));
            avn[0] = af.x; avn[1] = af.y; avn[2] = af.z; avn[3] = af.w;
            bvn = make_float4(0.f, 0.f, 0.f, 0.f);
            if (n0 + b_n < N) {
                const size_t wi = (size_t)(kn + b_k) * N + (n0 + b_n);
                if (f32) bvn = *(const float4*)((const float*)W + wi);
                else {
                    const ushort4 u = *(const ushort4*)((const us*)W + wi);
                    bvn = make_float4(bf2f(u.x), bf2f(u.y), bf2f(u.z), bf2f(u.w));
                }
            }
        }

        #pragma unroll
        for (int kk = 0; kk < 16; ++kk) {
            const float4 a4 = *(const float4*)&As[kk][ty << 2];
            const float4 b4 = *(const float4*)&Bs[kk][tx << 2];
            const float aarr[4] = {a4.x, a4.y, a4.z, a4.w};
            const float barr[4] = {b4.x, b4.y, b4.z, b4.w};
            #pragma unroll
            for (int i = 0; i < 4; ++i)
                #pragma unroll
                for (int j = 0; j < 4; ++j)
                    acc[i][j] = fmaf(aarr[i], barr[j], acc[i][j]);
        }
        __syncthreads();

        if (kn < K) {
            #pragma unroll
            for (int i = 0; i < 4; ++i) avp[i] = avn[i];
            bvp = bvn;
        }
    }

    float bvals[4];
    const bool colsok = (n0 + (tx << 2)) < N;
    #pragma unroll
    for (int j = 0; j < 4; ++j) {
        const int n = n0 + (tx << 2) + j;
        bvals[j] = (n < N) ? ldf(bias, n, f32) : 0.f;
    }
    float ps[4] = {0.f, 0.f, 0.f, 0.f}, pq[4] = {0.f, 0.f, 0.f, 0.f};
    #pragma unroll
    for (int i = 0; i < 4; ++i) {
        float4 hv;
        float* hvp = (float*)&hv;
        #pragma unroll
        for (int j = 0; j < 4; ++j) {
            const float v = acc[i][j] + bvals[j];
            hvp[j] = v;
            ps[j] += v;
            pq[j] = fmaf(v, v, pq[j]);
        }
        if (colsok)
            *(float4*)(H + (size_t)(m0 + (ty << 2) + i) * N + n0 + (tx << 2)) = hv;
    }
    #pragma unroll
    for (int j = 0; j < 4; ++j) {
        atomicAdd(&s_sum[(tx << 2) + j], ps[j]);
        atomicAdd(&s_sq[(tx << 2) + j], pq[j]);
    }
    __syncthreads();
    if (tid < 64) {
        const int n = n0 + tid;
        if (n < N) {
            atomicAdd(&stats_out[n], s_sum[tid]);
            atomicAdd(&stats_out[N + n], s_sq[tid]);
        }
    }
}

__global__ __launch_bounds__(256)
void finalize_kernel(const float* __restrict__ Hf, const float* __restrict__ stats,
                     const void* __restrict__ g, const void* __restrict__ bt,
                     float inv_m, void* __restrict__ out,
                     const int* __restrict__ pf32, int total)
{
    const int idx = blockIdx.x * 256 + threadIdx.x;
    if (idx >= total) return;
    const int f32 = *pf32;
    const int c = idx & 31;
    const float mu  = stats[c] * inv_m;
    const float var = stats[32 + c] * inv_m - mu * mu;
    const float a = ldf(g, c, f32) * rsqrtf(var + BN_EPS);
    const float b = ldf(bt, c, f32) - mu * a;
    const float v = fmaxf(fmaf(a, Hf[idx], b), 0.f);
    if (f32) ((float*)out)[idx] = v;
    else     ((us*)out)[idx] = f2bf(v);
}

extern "C" void kernel_launch(void* const* d_in, const int* in_sizes, int n_in,
                              void* d_out, int out_size, void* d_ws, size_t ws_size,
                              hipStream_t stream) {
    (void)in_sizes; (void)n_in; (void)out_size; (void)ws_size;
    const void* p0 = d_in[0];
    const void* f0 = d_in[1];
    const void* p1 = d_in[3];
    const void* f1 = d_in[4];
    const void* p2 = d_in[6];
    const void* f2 = d_in[7];
    const void* p3 = d_in[9];
    const void* f3 = d_in[10];
    const void* p4 = d_in[12];
    const void* f4 = d_in[13];
    const void *W1[4], *B1[4], *G1[4], *T1[4], *W2[4], *B2[4], *G2[4], *T2[4];
    for (int s = 0; s < 4; ++s) {
        const int b = 15 + s * 8;
        W1[s] = d_in[b + 0]; B1[s] = d_in[b + 1];
        G1[s] = d_in[b + 2]; T1[s] = d_in[b + 3];
        W2[s] = d_in[b + 4]; B2[s] = d_in[b + 5];
        G2[s] = d_in[b + 6]; T2[s] = d_in[b + 7];
    }

    // ---- workspace: proven 25,174,016-byte footprint ----
    float* stats = (float*)d_ws;
    float* st_a1 = stats + 0;
    float* st_a2 = stats + 512;
    float* st_b1 = stats + 1024;
    float* st_b2 = stats + 1280;
    float* st_c1 = stats + 1536;
    float* st_c2 = stats + 1664;
    float* st_d1 = stats + 1792;
    float* st_d2 = stats + 1856;
    int*   flag  = (int*)(stats + 1920);
    float* U = (float*)((char*)d_ws + 8192);
    float* H = U + 4194304;
    float* h2a = H + 262144;
    float* h2b = H + 524288;
    float* h2c = H + 1048576;
    float* h2d = U;
    // Stage-d scratch in [H, H+1MB) — dead between gemm2-c (last reader of H)
    // and gemm1-d (next writer). h2c at H+4MB untouched.
    float4* aosbuf = (float4*)H;                 // stages a-c AoS (<=64KB)
    float4* srtbuf = (float4*)H;                 // sorted coarse AoS, 256KB
    int*    jbuf   = (int*)(H + 65536);          // sorted coarse idx, 64KB
    int*    qidxbuf = (int*)(H + 81920);         // bin-sorted fine idx, 256KB
    int*    histbuf = (int*)(H + 147456);        // 1024 ints
    int*    cntbuf  = (int*)(H + 148480);        // 1024 ints

    hipMemsetAsync(d_ws, 0, 1920 * sizeof(float), stream);
    detect_kernel<<<1, 64, 0, stream>>>((const unsigned int*)G1[0], flag);

    // stage a: fine=3 (1024, c1=256), coarse=4 (256, c2=512); n2pb=32
    prep_aos_kernel<<<1, 256, 0, stream>>>(p4, aosbuf, flag, 256);
    knn_up_kernel<0, 8, 4><<<dim3(2, 8), 512, 0, stream>>>(
        p3, aosbuf, f4, nullptr, nullptr, nullptr, 0.f, U, flag, 32, 512);
    gemm1_bn_kernel<<<dim3(4, 16), 256, 0, stream>>>(
        f3, U, W1[0], B1[0], H, st_a1, flag, 1024, 256, 512, 256);
    gemm2_bn_kernel<<<dim3(4, 16), 256, 0, stream>>>(
        H, W2[0], B2[0], st_a1, G1[0], T1[0], 1.f / 1024.f,
        h2a, st_a2, flag, 1024, 256, 256);
    // stage b: fine=2 (4096, c1=128), coarse=3 (1024, c2=256); n2pb=128
    prep_aos_kernel<<<4, 256, 0, stream>>>(p3, aosbuf, flag, 1024);
    knn_up_kernel<1, 8, 16><<<dim3(8, 8), 512, 0, stream>>>(
        p2, aosbuf, h2a, st_a2, G2[0], T2[0], 1.f / 1024.f, U, flag, 128, 256);
    gemm1_bn_kernel<<<dim3(2, 64), 256, 0, stream>>>(
        f2, U, W1[1], B1[1], H, st_b1, flag, 4096, 128, 256, 128);
    gemm2_bn_kernel<<<dim3(2, 64), 256, 0, stream>>>(
        H, W2[1], B2[1], st_b1, G1[1], T1[1], 1.f / 4096.f,
        h2b, st_b2, flag, 4096, 128, 128);
    // stage c: fine=1 (16384, c1=64), coarse=2 (4096, c2=128); n2pb=512
    prep_aos_kernel<<<16, 256, 0, stream>>>(p2, aosbuf, flag, 4096);
    knn_up_kernel<1, 16, 32><<<dim3(32, 8), 1024, 0, stream>>>(
        p1, aosbuf, h2b, st_b2, G2[1], T2[1], 1.f / 4096.f, U, flag, 512, 128);
    gemm1_bn_kernel<<<dim3(1, 256), 256, 0, stream>>>(
        f1, U, W1[2], B1[2], H, st_c1, flag, 16384, 64, 128, 64);
    gemm2_bn_kernel<<<dim3(1, 256), 256, 0, stream>>>(
        H, W2[2], B2[2], st_c1, G1[2], T1[2], 1.f / 16384.f,
        h2c, st_c2, flag, 16384, 64, 64);
    // stage d: fine=0 (65536, c1=32), coarse=1 (16384, c2=64); n2pb=2048
    sort_aos_kernel<2048><<<8, 1024, 0, stream>>>(p1, flag, srtbuf, jbuf);
    hipMemsetAsync(histbuf, 0, 1024 * sizeof(int), stream);
    hist_kernel<<<256, 256, 0, stream>>>(p0, histbuf, flag, 65536, 8192);
    prefix_kernel<<<1, 64, 0, stream>>>(histbuf, cntbuf);
    scatter_kernel<<<256, 256, 0, stream>>>(p0, cntbuf, qidxbuf, flag, 65536, 8192);
    knn_win2_kernel<2048, 64, 256><<<dim3(32, 8), 512, 0, stream>>>(
        p0, srtbuf, jbuf, qidxbuf, h2c, st_c2, G2[2], T2[2],
        1.f / 16384.f, U, flag, 8192);
    gemm1_bn_kernel<<<dim3(1, 1024), 256, 0, stream>>>(
        f0, U, W1[3], B1[3], H, st_d1, flag, 65536, 32, 64, 32);
    gemm2_bn_kernel<<<dim3(1, 1024), 256, 0, stream>>>(
        H, W2[3], B2[3], st_d1, G1[3], T1[3], 1.f / 65536.f,
        h2d, st_d2, flag, 65536, 32, 32);
    finalize_kernel<<<(65536 * 32) / 256, 256, 0, stream>>>(
        h2d, st_d2, G2[3], T2[3], 1.f / 65536.f, d_out, flag, 65536 * 32);
}

// Round 10
// 500.062 us; speedup vs baseline: 1.2813x; 1.2813x over previous
//
#include <hip/hip_runtime.h>

#define BN_EPS 1e-5f

typedef unsigned short us;

__device__ __forceinline__ float bf2f(us u) {
    union { unsigned int i; float f; } v; v.i = ((unsigned int)u) << 16; return v.f;
}
__device__ __forceinline__ us f2bf(float f) {
    unsigned int x = __float_as_uint(f);
    x += 0x7fffu + ((x >> 16) & 1u);
    return (us)(x >> 16);
}
__device__ __forceinline__ float ldf(const void* p, size_t i, int f32) {
    return f32 ? ((const float*)p)[i] : bf2f(((const us*)p)[i]);
}

__global__ void detect_kernel(const unsigned int* __restrict__ g, int* __restrict__ flag) {
    if (threadIdx.x == 0 && blockIdx.x == 0)
        *flag = ((g[0] & 0xFFFFu) == 0u) ? 1 : 0;
}

// ---------------------------------------------------------------------------
// Prep: coarse points -> f32 AoS (2x, 2y, 2z, s2).  s2 uses the EXACT _rn
// sequence; doubling via x+x is exact (pow2 scaling), so the scan's
// fma(pz,2qz,fma(py,2qy,px*2qx)) == 2*dot bitwise (validated by R14/R16).
// ---------------------------------------------------------------------------
__global__ __launch_bounds__(256)
void prep_aos_kernel(const void* __restrict__ p, float4* __restrict__ aos,
                     const int* __restrict__ pf32, int n)
{
    const int i = blockIdx.x * 256 + threadIdx.x;
    if (i >= n) return;
    const int f32 = *pf32;
    const float x = ldf(p, (size_t)3 * i + 0, f32);
    const float y = ldf(p, (size_t)3 * i + 1, f32);
    const float z = ldf(p, (size_t)3 * i + 2, f32);
    const float s2 = __fadd_rn(__fadd_rn(__fmul_rn(x, x), __fmul_rn(y, y)), __fmul_rn(z, z));
    aos[i] = make_float4(__fadd_rn(x, x), __fadd_rn(y, y), __fadd_rn(z, z), s2);
}

// Branch-free lexicographic merge of two lex-sorted triples -> lex-top-3 of
// the union (exact for the strict total order (d, idx); indices distinct).
__device__ __forceinline__ void lexmerge33(
    const float a0, const int A0, const float a1, const int A1, const float a2, const int A2,
    const float b0, const int B0, const float b1, const int B1, const float b2, const int B2,
    float& m0, int& M0, float& m1, int& M1, float& m2, int& M2)
{
    const bool c1 = (a0 < b0) || (a0 == b0 && A0 < B0);
    m0 = c1 ? a0 : b0;  M0 = c1 ? A0 : B0;
    const float hAd = c1 ? a1 : a0;  const int hAi = c1 ? A1 : A0;
    const float hBd = c1 ? b0 : b1;  const int hBi = c1 ? B0 : B1;
    const bool c2 = (hAd < hBd) || (hAd == hBd && hAi < hBi);
    m1 = c2 ? hAd : hBd;  M1 = c2 ? hAi : hBi;
    const float gAd = c2 ? (c1 ? a2 : a1) : hAd;  const int gAi = c2 ? (c1 ? A2 : A1) : hAi;
    const float gBd = c2 ? hBd : (c1 ? b1 : b2);  const int gBi = c2 ? hBi : (c1 ? B1 : B2);
    const bool c3 = (gAd < gBd) || (gAd == gBd && gAi < gBi);
    m2 = c3 ? gAd : gBd;  M2 = c3 ? gAi : gBi;
}

// ---------------------------------------------------------------------------
// kNN(k=3) + inverse-d2 interpolation.
// SELECTION BIT-IDENTICAL to the R11-verified formula:
//   d2 = (s1 + s2) - 2*dot, 2*dot realized via doubled coords (exact),
//   per-slice strict-< insert over increasing j, lex (d, idx) merge.
// w = 1/max(d2,1e-16); up = fma(w2,v2,fma(w1,v1,w0*v0)) / ((w0+w1)+w2).
//
// R20 = R16 verbatim (best verified total, 500.46us). The windowed/spatial
// variants (R18/R19) passed correctness but regressed perf 2x; the brute
// scan's ~90 cy/wave-candidate floor reproduced across LDS, flat-global,
// and SGPR-base paths — banked as the practical structure.
// ---------------------------------------------------------------------------
template<int MODE, int SPLIT, int LEN>
__global__ __launch_bounds__(64 * SPLIT, 8)
void knn_up_kernel(
    const void* __restrict__ p_fine,
    const float4* __restrict__ aos,
    const void* __restrict__ f_coarse,
    const float* __restrict__ stats,
    const void* __restrict__ gamma,
    const void* __restrict__ beta,
    float inv_n2,
    float* __restrict__ up_out,
    const int* __restrict__ pf32,
    int n2pb, int c2)
{
    __shared__ float mrg_d[SPLIT * 64 * 3];
    __shared__ int   mrg_i[SPLIT * 64 * 3];
    __shared__ float aff_a[256], aff_b[256];
    __shared__ int   s_idx[64][3];
    __shared__ float s_w[64][3];

    const int f32 = *pf32;
    const int tid = threadIdx.x;
    const int lane = tid & 63;
    const int wv = tid >> 6;
    const int cbase = blockIdx.y * n2pb;
    const int row0 = (blockIdx.y * gridDim.x + blockIdx.x) * 64;

    if (MODE == 1) {
        for (int c = tid; c < c2; c += 64 * SPLIT) {
            float mu  = stats[c] * inv_n2;
            float var = stats[c2 + c] * inv_n2 - mu * mu;
            float a = ldf(gamma, c, f32) * rsqrtf(var + BN_EPS);
            aff_a[c] = a;
            aff_b[c] = ldf(beta, c, f32) - mu * a;
        }
    }

    // phase 1: per-wave slice scan (R11-exact selection; candidates wave-uniform)
    {
        const int row = row0 + lane;
        const size_t b = (size_t)row * 3;
        const float px = ldf(p_fine, b + 0, f32);
        const float py = ldf(p_fine, b + 1, f32);
        const float pz = ldf(p_fine, b + 2, f32);
        const float s1 = __fadd_rn(__fadd_rn(__fmul_rn(px, px), __fmul_rn(py, py)),
                                   __fmul_rn(pz, pz));
        const int jb = wv * LEN;
        const float4* __restrict__ sl = aos + cbase + jb;
        float t0 = 1e30f, t1 = 1e30f, t2 = 1e30f;
        int i0 = jb, i1 = jb, i2 = jb;

#define KNN_UPD(CQ, JJ) {                                                     \
        const float dot2 = fmaf(pz, (CQ).z, fmaf(py, (CQ).y,                  \
                                __fmul_rn(px, (CQ).x)));                      \
        const float d = __fsub_rn(__fadd_rn(s1, (CQ).w), dot2);               \
        const int jj = (JJ);                                                  \
        const bool a0 = d < t0, a1 = d < t1, a2 = d < t2;                     \
        t2 = a1 ? t1 : (a2 ? d : t2);  i2 = a1 ? i1 : (a2 ? jj : i2);         \
        t1 = a0 ? t0 : (a1 ? d : t1);  i1 = a0 ? i0 : (a1 ? jj : i1);         \
        t0 = a0 ? d  : t0;             i0 = a0 ? jj : i0; }

        float4 ca = sl[0], cb = sl[1], cc = sl[2], cd = sl[3];
        for (int t = 0; t < LEN; t += 4) {
            float4 na, nb, nc, nd;
            const bool more = (t + 4) < LEN;
            if (more) { na = sl[t + 4]; nb = sl[t + 5]; nc = sl[t + 6]; nd = sl[t + 7]; }
            KNN_UPD(ca, jb + t + 0);
            KNN_UPD(cb, jb + t + 1);
            KNN_UPD(cc, jb + t + 2);
            KNN_UPD(cd, jb + t + 3);
            if (more) { ca = na; cb = nb; cc = nc; cd = nd; }
        }
#undef KNN_UPD

        const int mb = (wv * 64 + lane) * 3;
        mrg_d[mb + 0] = t0;  mrg_i[mb + 0] = cbase + i0;
        mrg_d[mb + 1] = t1;  mrg_i[mb + 1] = cbase + i1;
        mrg_d[mb + 2] = t2;  mrg_i[mb + 2] = cbase + i2;
    }
    __syncthreads();

    // tree-fold the SPLIT per-slice triples (lex merge, order-invariant)
    if (tid < 64) {
        float d0 = mrg_d[tid * 3 + 0], d1 = mrg_d[tid * 3 + 1], d2 = mrg_d[tid * 3 + 2];
        int   j0 = mrg_i[tid * 3 + 0], j1 = mrg_i[tid * 3 + 1], j2 = mrg_i[tid * 3 + 2];
        #pragma unroll
        for (int w = 1; w < SPLIT; ++w) {
            const int mb = (w * 64 + tid) * 3;
            const float e0 = mrg_d[mb + 0], e1 = mrg_d[mb + 1], e2 = mrg_d[mb + 2];
            const int   k0 = mrg_i[mb + 0], k1 = mrg_i[mb + 1], k2 = mrg_i[mb + 2];
            float n0, n1, n2v; int ni0, ni1, ni2;
            lexmerge33(d0, j0, d1, j1, d2, j2,
                       e0, k0, e1, k1, e2, k2,
                       n0, ni0, n1, ni1, n2v, ni2);
            d0 = n0; j0 = ni0; d1 = n1; j1 = ni1; d2 = n2v; j2 = ni2;
        }
        s_idx[tid][0] = j0;  s_w[tid][0] = __fdiv_rn(1.0f, fmaxf(d0, 1e-16f));
        s_idx[tid][1] = j1;  s_w[tid][1] = __fdiv_rn(1.0f, fmaxf(d1, 1e-16f));
        s_idx[tid][2] = j2;  s_w[tid][2] = __fdiv_rn(1.0f, fmaxf(d2, 1e-16f));
    }
    __syncthreads();

    // phase 2: up = weighted gather, coalesced over channels
    for (int p = wv; p < 64; p += SPLIT) {
        const int row = row0 + p;
        const int g0 = s_idx[p][0], g1 = s_idx[p][1], g2 = s_idx[p][2];
        const float w0 = s_w[p][0], w1 = s_w[p][1], w2 = s_w[p][2];
        const float den = __fadd_rn(__fadd_rn(w0, w1), w2);
        float* __restrict__ urow = up_out + (size_t)row * c2;
        for (int c = lane; c < c2; c += 64) {
            float v0, v1, v2;
            if (MODE == 0) {
                v0 = ldf(f_coarse, (size_t)g0 * c2 + c, f32);
                v1 = ldf(f_coarse, (size_t)g1 * c2 + c, f32);
                v2 = ldf(f_coarse, (size_t)g2 * c2 + c, f32);
            } else {
                const float* fc = (const float*)f_coarse;
                const float aa = aff_a[c], bb = aff_b[c];
                v0 = fmaxf(aa * fc[(size_t)g0 * c2 + c] + bb, 0.f);
                v1 = fmaxf(aa * fc[(size_t)g1 * c2 + c] + bb, 0.f);
                v2 = fmaxf(aa * fc[(size_t)g2 * c2 + c] + bb, 0.f);
            }
            const float num = fmaf(w2, v2, fmaf(w1, v1, __fmul_rn(w0, v0)));
            urow[c] = __fdiv_rn(num, den);
        }
    }
}

// ---------------------------------------------------------------------------
// GEMM1: H = [f_fine | up] @ W + bias; register-prefetch double buffering;
// fused atomic column sum/sumsq. 64x64 tile, TK=16, 4x4/thread. c1 % 16 == 0.
// ---------------------------------------------------------------------------
__global__ __launch_bounds__(256)
void gemm1_bn_kernel(const void* __restrict__ Ffine,
                     const float* __restrict__ Up,
                     const void* __restrict__ W,
                     const void* __restrict__ bias,
                     float* __restrict__ H,
                     float* __restrict__ stats_out,
                     const int* __restrict__ pf32,
                     int M, int c1, int c2, int N)
{
    __shared__ __align__(16) float As[16][68];
    __shared__ __align__(16) float Bs[16][68];
    __shared__ float s_sum[64], s_sq[64];

    const int f32 = *pf32;
    const int K = c1 + c2;
    const int tid = threadIdx.x;
    const int tx = tid & 15, ty = tid >> 4;
    const int n0 = blockIdx.x * 64, m0 = blockIdx.y * 64;

    if (tid < 64) { s_sum[tid] = 0.f; s_sq[tid] = 0.f; }

    const int a_m = tid >> 2;
    const int a_k = (tid & 3) << 2;
    const int b_k = tid >> 4;
    const int b_n = (tid & 15) << 2;
    const int row = m0 + a_m;

    float avp[4]; float4 bvp;
    {
        const int k = a_k;
        if (k < c1) {
            if (f32) {
                const float4 v = *(const float4*)((const float*)Ffine + (size_t)row * c1 + k);
                avp[0] = v.x; avp[1] = v.y; avp[2] = v.z; avp[3] = v.w;
            } else {
                const ushort4 u = *(const ushort4*)((const us*)Ffine + (size_t)row * c1 + k);
                avp[0] = bf2f(u.x); avp[1] = bf2f(u.y); avp[2] = bf2f(u.z); avp[3] = bf2f(u.w);
            }
        } else {
            const float4 v = *(const float4*)(Up + (size_t)row * c2 + (k - c1));
            avp[0] = v.x; avp[1] = v.y; avp[2] = v.z; avp[3] = v.w;
        }
        bvp = make_float4(0.f, 0.f, 0.f, 0.f);
        if (n0 + b_n < N) {
            const size_t wi = (size_t)b_k * N + (n0 + b_n);
            if (f32) bvp = *(const float4*)((const float*)W + wi);
            else {
                const ushort4 u = *(const ushort4*)((const us*)W + wi);
                bvp = make_float4(bf2f(u.x), bf2f(u.y), bf2f(u.z), bf2f(u.w));
            }
        }
    }

    float acc[4][4] = {};

    for (int k0 = 0; k0 < K; k0 += 16) {
        #pragma unroll
        for (int i = 0; i < 4; ++i) As[a_k + i][a_m] = avp[i];
        *(float4*)&Bs[b_k][b_n] = bvp;
        __syncthreads();

        float avn[4]; float4 bvn;
        const int kn = k0 + 16;
        if (kn < K) {
            const int k = kn + a_k;
            if (k < c1) {
                if (f32) {
                    const float4 v = *(const float4*)((const float*)Ffine + (size_t)row * c1 + k);
                    avn[0] = v.x; avn[1] = v.y; avn[2] = v.z; avn[3] = v.w;
                } else {
                    const ushort4 u = *(const ushort4*)((const us*)Ffine + (size_t)row * c1 + k);
                    avn[0] = bf2f(u.x); avn[1] = bf2f(u.y); avn[2] = bf2f(u.z); avn[3] = bf2f(u.w);
                }
            } else {
                const float4 v = *(const float4*)(Up + (size_t)row * c2 + (k - c1));
                avn[0] = v.x; avn[1] = v.y; avn[2] = v.z; avn[3] = v.w;
            }
            bvn = make_float4(0.f, 0.f, 0.f, 0.f);
            if (n0 + b_n < N) {
                const size_t wi = (size_t)(kn + b_k) * N + (n0 + b_n);
                if (f32) bvn = *(const float4*)((const float*)W + wi);
                else {
                    const ushort4 u = *(const ushort4*)((const us*)W + wi);
                    bvn = make_float4(bf2f(u.x), bf2f(u.y), bf2f(u.z), bf2f(u.w));
                }
            }
        }

        #pragma unroll
        for (int kk = 0; kk < 16; ++kk) {
            const float4 a4 = *(const float4*)&As[kk][ty << 2];
            const float4 b4 = *(const float4*)&Bs[kk][tx << 2];
            const float aarr[4] = {a4.x, a4.y, a4.z, a4.w};
            const float barr[4] = {b4.x, b4.y, b4.z, b4.w};
            #pragma unroll
            for (int i = 0; i < 4; ++i)
                #pragma unroll
                for (int j = 0; j < 4; ++j)
                    acc[i][j] = fmaf(aarr[i], barr[j], acc[i][j]);
        }
        __syncthreads();

        if (kn < K) {
            #pragma unroll
            for (int i = 0; i < 4; ++i) avp[i] = avn[i];
            bvp = bvn;
        }
    }

    float bvals[4];
    const bool colsok = (n0 + (tx << 2)) < N;
    #pragma unroll
    for (int j = 0; j < 4; ++j) {
        const int n = n0 + (tx << 2) + j;
        bvals[j] = (n < N) ? ldf(bias, n, f32) : 0.f;
    }
    float ps[4] = {0.f, 0.f, 0.f, 0.f}, pq[4] = {0.f, 0.f, 0.f, 0.f};
    #pragma unroll
    for (int i = 0; i < 4; ++i) {
        float4 hv;
        float* hvp = (float*)&hv;
        #pragma unroll
        for (int j = 0; j < 4; ++j) {
            const float v = acc[i][j] + bvals[j];
            hvp[j] = v;
            ps[j] += v;
            pq[j] = fmaf(v, v, pq[j]);
        }
        if (colsok)
            *(float4*)(H + (size_t)(m0 + (ty << 2) + i) * N + n0 + (tx << 2)) = hv;
    }
    #pragma unroll
    for (int j = 0; j < 4; ++j) {
        atomicAdd(&s_sum[(tx << 2) + j], ps[j]);
        atomicAdd(&s_sq[(tx << 2) + j], pq[j]);
    }
    __syncthreads();
    if (tid < 64) {
        const int n = n0 + tid;
        if (n < N) {
            atomicAdd(&stats_out[n], s_sum[tid]);
            atomicAdd(&stats_out[N + n], s_sq[tid]);
        }
    }
}

// ---------------------------------------------------------------------------
// GEMM2: H = relu(BN(A)) @ W + bias; register-prefetch double buffering;
// affine on load; fused atomic stats out.
// ---------------------------------------------------------------------------
__global__ __launch_bounds__(256)
void gemm2_bn_kernel(const float* __restrict__ A,
                     const void* __restrict__ W,
                     const void* __restrict__ bias,
                     const float* __restrict__ stats_in,
                     const void* __restrict__ g_in,
                     const void* __restrict__ bt_in,
                     float inv_m,
                     float* __restrict__ H,
                     float* __restrict__ stats_out,
                     const int* __restrict__ pf32,
                     int M, int K, int N)
{
    __shared__ __align__(16) float As[16][68];
    __shared__ __align__(16) float Bs[16][68];
    __shared__ float aff_a[256], aff_b[256];
    __shared__ float s_sum[64], s_sq[64];

    const int f32 = *pf32;
    const int tid = threadIdx.x;
    const int tx = tid & 15, ty = tid >> 4;
    const int n0 = blockIdx.x * 64, m0 = blockIdx.y * 64;

    for (int c = tid; c < K; c += 256) {
        float mu  = stats_in[c] * inv_m;
        float var = stats_in[K + c] * inv_m - mu * mu;
        float a = ldf(g_in, c, f32) * rsqrtf(var + BN_EPS);
        aff_a[c] = a; aff_b[c] = ldf(bt_in, c, f32) - mu * a;
    }
    if (tid < 64) { s_sum[tid] = 0.f; s_sq[tid] = 0.f; }
    __syncthreads();

    const int a_m = tid >> 2;
    const int a_k = (tid & 3) << 2;
    const int b_k = tid >> 4;
    const int b_n = (tid & 15) << 2;
    const int row = m0 + a_m;

    float avp[4]; float4 bvp;
    {
        const float4 af = *(const float4*)(A + (size_t)row * K + a_k);
        avp[0] = af.x; avp[1] = af.y; avp[2] = af.z; avp[3] = af.w;
        bvp = make_float4(0.f, 0.f, 0.f, 0.f);
        if (n0 + b_n < N) {
            const size_t wi = (size_t)b_k * N + (n0 + b_n);
            if (f32) bvp = *(const float4*)((const float*)W + wi);
            else {
                const ushort4 u = *(const ushort4*)((const us*)W + wi);
                bvp = make_float4(bf2f(u.x), bf2f(u.y), bf2f(u.z), bf2f(u.w));
            }
        }
    }

    float acc[4][4] = {};

    for (int k0 = 0; k0 < K; k0 += 16) {
        #pragma unroll
        for (int i = 0; i < 4; ++i)
            As[a_k + i][a_m] = fmaxf(fmaf(aff_a[k0 + a_k + i], avp[i], aff_b[k0 + a_k + i]), 0.f);
        *(float4*)&Bs[b_k][b_n] = bvp;
        __syncthreads();

        float avn[4]; float4 bvn;
        const int kn = k0 + 16;
        if (kn < K) {
            const float4 af = *(const float4*)(A + (size_t)row * K + (kn + a_k));
            avn[0] = af.x; avn[1] = af.y; avn[2] = af.z; avn[3] = af.w;
            bvn = make_float4(0.f, 0.f, 0.f, 0.f);
            if (n0 + b_n < N) {
                const size_t wi = (size_t)(kn + b_k) * N + (n0 + b_n);
                if (f32) bvn = *(const float4*)((const float*)W + wi);
                else {
                    const ushort4 u = *(const ushort4*)((const us*)W + wi);
                    bvn = make_float4(bf2f(u.x), bf2f(u.y), bf2f(u.z), bf2f(u.w));
                }
            }
        }

        #pragma unroll
        for (int kk = 0; kk < 16; ++kk) {
            const float4 a4 = *(const float4*)&As[kk][ty << 2];
            const float4 b4 = *(const float4*)&Bs[kk][tx << 2];
            const float aarr[4] = {a4.x, a4.y, a4.z, a4.w};
            const float barr[4] = {b4.x, b4.y, b4.z, b4.w};
            #pragma unroll
            for (int i = 0; i < 4; ++i)
                #pragma unroll
                for (int j = 0; j < 4; ++j)
                    acc[i][j] = fmaf(aarr[i], barr[j], acc[i][j]);
        }
        __syncthreads();

        if (kn < K) {
            #pragma unroll
            for (int i = 0; i < 4; ++i) avp[i] = avn[i];
            bvp = bvn;
        }
    }

    float bvals[4];
    const bool colsok = (n0 + (tx << 2)) < N;
    #pragma unroll
    for (int j = 0; j < 4; ++j) {
        const int n = n0 + (tx << 2) + j;
        bvals[j] = (n < N) ? ldf(bias, n, f32) : 0.f;
    }
    float ps[4] = {0.f, 0.f, 0.f, 0.f}, pq[4] = {0.f, 0.f, 0.f, 0.f};
    #pragma unroll
    for (int i = 0; i < 4; ++i) {
        float4 hv;
        float* hvp = (float*)&hv;
        #pragma unroll
        for (int j = 0; j < 4; ++j) {
            const float v = acc[i][j] + bvals[j];
            hvp[j] = v;
            ps[j] += v;
            pq[j] = fmaf(v, v, pq[j]);
        }
        if (colsok)
            *(float4*)(H + (size_t)(m0 + (ty << 2) + i) * N + n0 + (tx << 2)) = hv;
    }
    #pragma unroll
    for (int j = 0; j < 4; ++j) {
        atomicAdd(&s_sum[(tx << 2) + j], ps[j]);
        atomicAdd(&s_sq[(tx << 2) + j], pq[j]);
    }
    __syncthreads();
    if (tid < 64) {
        const int n = n0 + tid;
        if (n < N) {
            atomicAdd(&stats_out[n], s_sum[tid]);
            atomicAdd(&stats_out[N + n], s_sq[tid]);
        }
    }
}

__global__ __launch_bounds__(256)
void finalize_kernel(const float* __restrict__ Hf, const float* __restrict__ stats,
                     const void* __restrict__ g, const void* __restrict__ bt,
                     float inv_m, void* __restrict__ out,
                     const int* __restrict__ pf32, int total)
{
    const int idx = blockIdx.x * 256 + threadIdx.x;
    if (idx >= total) return;
    const int f32 = *pf32;
    const int c = idx & 31;
    const float mu  = stats[c] * inv_m;
    const float var = stats[32 + c] * inv_m - mu * mu;
    const float a = ldf(g, c, f32) * rsqrtf(var + BN_EPS);
    const float b = ldf(bt, c, f32) - mu * a;
    const float v = fmaxf(fmaf(a, Hf[idx], b), 0.f);
    if (f32) ((float*)out)[idx] = v;
    else     ((us*)out)[idx] = f2bf(v);
}

extern "C" void kernel_launch(void* const* d_in, const int* in_sizes, int n_in,
                              void* d_out, int out_size, void* d_ws, size_t ws_size,
                              hipStream_t stream) {
    (void)in_sizes; (void)n_in; (void)out_size; (void)ws_size;
    const void* p0 = d_in[0];
    const void* f0 = d_in[1];
    const void* p1 = d_in[3];
    const void* f1 = d_in[4];
    const void* p2 = d_in[6];
    const void* f2 = d_in[7];
    const void* p3 = d_in[9];
    const void* f3 = d_in[10];
    const void* p4 = d_in[12];
    const void* f4 = d_in[13];
    const void *W1[4], *B1[4], *G1[4], *T1[4], *W2[4], *B2[4], *G2[4], *T2[4];
    for (int s = 0; s < 4; ++s) {
        const int b = 15 + s * 8;
        W1[s] = d_in[b + 0]; B1[s] = d_in[b + 1];
        G1[s] = d_in[b + 2]; T1[s] = d_in[b + 3];
        W2[s] = d_in[b + 4]; B2[s] = d_in[b + 5];
        G2[s] = d_in[b + 6]; T2[s] = d_in[b + 7];
    }

    // ---- workspace: proven 25,174,016-byte footprint ----
    float* stats = (float*)d_ws;
    float* st_a1 = stats + 0;
    float* st_a2 = stats + 512;
    float* st_b1 = stats + 1024;
    float* st_b2 = stats + 1280;
    float* st_c1 = stats + 1536;
    float* st_c2 = stats + 1664;
    float* st_d1 = stats + 1792;
    float* st_d2 = stats + 1856;
    int*   flag  = (int*)(stats + 1920);
    float* U = (float*)((char*)d_ws + 8192);
    float* H = U + 4194304;
    float* h2a = H + 262144;
    float* h2b = H + 524288;
    float* h2c = H + 1048576;
    float* h2d = U;
    // AoS scratch lives at [H, H+262144 floats): dead in each knn's window
    // (H is only written by the gemm1 that FOLLOWS the knn; prior gemm1
    // output there was consumed by the preceding gemm2). Each prep runs
    // immediately before its knn, stream-serialized.
    float4* aosbuf = (float4*)H;

    hipMemsetAsync(d_ws, 0, 1920 * sizeof(float), stream);
    detect_kernel<<<1, 64, 0, stream>>>((const unsigned int*)G1[0], flag);

    // stage a: fine=3 (1024, c1=256), coarse=4 (256, c2=512); n2pb=32
    prep_aos_kernel<<<1, 256, 0, stream>>>(p4, aosbuf, flag, 256);
    knn_up_kernel<0, 8, 4><<<dim3(2, 8), 512, 0, stream>>>(
        p3, aosbuf, f4, nullptr, nullptr, nullptr, 0.f, U, flag, 32, 512);
    gemm1_bn_kernel<<<dim3(4, 16), 256, 0, stream>>>(
        f3, U, W1[0], B1[0], H, st_a1, flag, 1024, 256, 512, 256);
    gemm2_bn_kernel<<<dim3(4, 16), 256, 0, stream>>>(
        H, W2[0], B2[0], st_a1, G1[0], T1[0], 1.f / 1024.f,
        h2a, st_a2, flag, 1024, 256, 256);
    // stage b: fine=2 (4096, c1=128), coarse=3 (1024, c2=256); n2pb=128
    prep_aos_kernel<<<4, 256, 0, stream>>>(p3, aosbuf, flag, 1024);
    knn_up_kernel<1, 8, 16><<<dim3(8, 8), 512, 0, stream>>>(
        p2, aosbuf, h2a, st_a2, G2[0], T2[0], 1.f / 1024.f, U, flag, 128, 256);
    gemm1_bn_kernel<<<dim3(2, 64), 256, 0, stream>>>(
        f2, U, W1[1], B1[1], H, st_b1, flag, 4096, 128, 256, 128);
    gemm2_bn_kernel<<<dim3(2, 64), 256, 0, stream>>>(
        H, W2[1], B2[1], st_b1, G1[1], T1[1], 1.f / 4096.f,
        h2b, st_b2, flag, 4096, 128, 128);
    // stage c: fine=1 (16384, c1=64), coarse=2 (4096, c2=128); n2pb=512
    prep_aos_kernel<<<16, 256, 0, stream>>>(p2, aosbuf, flag, 4096);
    knn_up_kernel<1, 16, 32><<<dim3(32, 8), 1024, 0, stream>>>(
        p1, aosbuf, h2b, st_b2, G2[1], T2[1], 1.f / 4096.f, U, flag, 512, 128);
    gemm1_bn_kernel<<<dim3(1, 256), 256, 0, stream>>>(
        f1, U, W1[2], B1[2], H, st_c1, flag, 16384, 64, 128, 64);
    gemm2_bn_kernel<<<dim3(1, 256), 256, 0, stream>>>(
        H, W2[2], B2[2], st_c1, G1[2], T1[2], 1.f / 16384.f,
        h2c, st_c2, flag, 16384, 64, 64);
    // stage d: fine=0 (65536, c1=32), coarse=1 (16384, c2=64); n2pb=2048
    prep_aos_kernel<<<64, 256, 0, stream>>>(p1, aosbuf, flag, 16384);
    knn_up_kernel<1, 8, 256><<<dim3(128, 8), 512, 0, stream>>>(
        p0, aosbuf, h2c, st_c2, G2[2], T2[2], 1.f / 16384.f, U, flag, 2048, 64);
    gemm1_bn_kernel<<<dim3(1, 1024), 256, 0, stream>>>(
        f0, U, W1[3], B1[3], H, st_d1, flag, 65536, 32, 64, 32);
    gemm2_bn_kernel<<<dim3(1, 1024), 256, 0, stream>>>(
        H, W2[3], B2[3], st_d1, G1[3], T1[3], 1.f / 65536.f,
        h2d, st_d2, flag, 65536, 32, 32);
    finalize_kernel<<<(65536 * 32) / 256, 256, 0, stream>>>(
        h2d, st_d2, G2[3], T2[3], 1.f / 65536.f, d_out, flag, 65536 * 32);
}